// Round 8
// baseline (173.290 us; speedup 1.0000x reference)
//
#include <hip/hip_runtime.h>

// VarlenAttention MI355X — round 13: GLOBAL-DIRECT RETRY, VGPR-FIXED, 1-WAVE BLOCKS.
// r10's global-direct regressed (90us) with VGPR_Count=52: compiler targeted 8
// waves/EU -> no registers for the 16 in-flight fragments -> serialized
// load->wait->use at ~400cyc each. Fix: amdgpu_waves_per_eu(2,4) (~170 VGPR
// budget) so both K-sets + V-set stay resident. Structure:
//  - 1-wave blocks (64 thr), grid (T/16)*H = 3072: NO barriers, no inter-wave
//    coupling, per-16-row k-trimming, up to 4 independent waves/SIMD.
//  - software pipeline: K(n+1) loads issued at top of iter n (full-iter cover);
//    V(n+1) issued right after PV(n) consumes V(n) (~400cyc cover); seg(n+1)
//    after softmax(n). Compiler emits counted vmcnt per register use.
//  - swapped-operand MFMA (S^T), pi-permuted Vb, exp2-folded softmax (r9).
//  - h = blockIdx&15 -> head pinned to XCD h%8, matching prepass placement (r11).
// r12 post-mortem: setprio+2-deep on the staged kernel was neutral (-1.8);
// issue accounting shows ~20% issue utilization, stall-bound at 3 waves/SIMD.
constexpr int NSEG = 8;
constexpr int H    = 16;
constexpr int D    = 64;
constexpr int BK   = 64;
constexpr int LDKP = D + 8;   // prepass/fallback padded layout

typedef __attribute__((ext_vector_type(8))) short short8v;
typedef __attribute__((ext_vector_type(4))) short short4v;
typedef __attribute__((ext_vector_type(4))) float floatx4;

__device__ inline short f2bf(float f) {  // RNE fp32 -> bf16
    union { float f; unsigned u; } x; x.f = f;
    unsigned r = x.u + 0x7FFFu + ((x.u >> 16) & 1u);
    return (short)(r >> 16);
}

__device__ inline unsigned cvtpk(float lo, float hi) {  // 2 f32 -> packed bf16x2
    unsigned r;
    asm("v_cvt_pk_bf16_f32 %0, %1, %2" : "=v"(r) : "v"(lo), "v"(hi));
    return r;
}

// ---- pre-pass: Kb[h][t][d], Vb[h][d][pi(t)], segArr[t] --------------------
// blockIdx = chunk*H + h -> writer XCD == reader XCD == h%8 (r11, kept).
// V column permutation per 8-key group t8: first 4 keys at c0, last 4 at
// c0+8, c0 = (t8&32)|((t8&8)<<1)|((t8&16)>>2)  (validated r9/r10).
__global__ __launch_bounds__(256)
void prepass_kv(const float* __restrict__ K, const float* __restrict__ V,
                const int* __restrict__ cuk,
                short* __restrict__ Kb, short* __restrict__ Vb,
                int* __restrict__ segArr, int T)
{
    __shared__ short sVT[D][LDKP];
    const int tid = threadIdx.x;
    const int h  = blockIdx.x & (H - 1);
    const int t0 = (blockIdx.x >> 4) << 6;
    #pragma unroll
    for (int it = 0; it < 2; ++it) {
        int s  = tid + it * 256;
        int tl = s >> 3;
        int d8 = (s & 7) << 3;
        int t  = t0 + tl;
        const float* kp = K + ((size_t)t * H + h) * D + d8;
        float4 a = *(const float4*)kp;
        float4 b = *(const float4*)(kp + 4);
        short8v ks;
        ks[0]=f2bf(a.x); ks[1]=f2bf(a.y); ks[2]=f2bf(a.z); ks[3]=f2bf(a.w);
        ks[4]=f2bf(b.x); ks[5]=f2bf(b.y); ks[6]=f2bf(b.z); ks[7]=f2bf(b.w);
        *(short8v*)&Kb[((size_t)h * T + t) * D + d8] = ks;
        const float* vp = V + ((size_t)t * H + h) * D + d8;
        float4 c = *(const float4*)vp;
        float4 e = *(const float4*)(vp + 4);
        sVT[d8+0][tl]=f2bf(c.x); sVT[d8+1][tl]=f2bf(c.y);
        sVT[d8+2][tl]=f2bf(c.z); sVT[d8+3][tl]=f2bf(c.w);
        sVT[d8+4][tl]=f2bf(e.x); sVT[d8+5][tl]=f2bf(e.y);
        sVT[d8+6][tl]=f2bf(e.z); sVT[d8+7][tl]=f2bf(e.w);
    }
    if (h == 0 && tid < 64) {
        int t = t0 + tid;
        int s = 0;
        #pragma unroll
        for (int i = 1; i < NSEG; ++i) s += (t >= cuk[i]) ? 1 : 0;
        segArr[t] = s;
    }
    __syncthreads();
    #pragma unroll
    for (int it = 0; it < 2; ++it) {
        int s  = tid + it * 256;
        int d  = s >> 3;
        int t8 = (s & 7) << 3;
        int c0 = (t8 & 32) | ((t8 & 8) << 1) | ((t8 & 16) >> 2);  // pi^-1
        short* vb = &Vb[((size_t)h * D + d) * T + t0];
        *(short4v*)&vb[c0]     = *(const short4v*)&sVT[d][t8];
        *(short4v*)&vb[c0 + 8] = *(const short4v*)&sVT[d][t8 + 4];
    }
}

// ---- main: 1-wave blocks, global-direct fragments, reg pipeline -----------
__global__ __launch_bounds__(64) __attribute__((amdgpu_waves_per_eu(2, 4)))
void varlen_attn13(const float* __restrict__ Q,
                   const short* __restrict__ Kb, const short* __restrict__ Vb,
                   const int* __restrict__ segArr,
                   const int* __restrict__ cuq, const int* __restrict__ cuk,
                   float* __restrict__ O, int T)
{
    __shared__ float fsc[16][68];   // wave-private O-transpose scratch (4.4KB)

    const int lane = threadIdx.x & 63;
    const int quad = lane >> 4;
    const int l15  = lane & 15;
    const int h     = blockIdx.x & (H - 1);      // XCD = h%8 (matches prepass)
    const int qbase = (blockIdx.x >> 4) << 4;    // 16 q rows per wave

    const int q1 = cuq[1], q2 = cuq[2], q3 = cuq[3], q4 = cuq[4],
              q5 = cuq[5], q6 = cuq[6], q7 = cuq[7];
    const int c0 = cuk[0], c1 = cuk[1], c2 = cuk[2], c3 = cuk[3], c4 = cuk[4],
              c5 = cuk[5], c6 = cuk[6], c7 = cuk[7], c8 = cuk[8];

    // per-wave k-range (16 q rows -> tight trimming)
    int tB = qbase + 15;
    int sA = (qbase>=q1)+(qbase>=q2)+(qbase>=q3)+(qbase>=q4)
           + (qbase>=q5)+(qbase>=q6)+(qbase>=q7);
    int sB = (tB>=q1)+(tB>=q2)+(tB>=q3)+(tB>=q4)+(tB>=q5)+(tB>=q6)+(tB>=q7);
    int k_start = c0;
    k_start = (sA>0)?c1:k_start; k_start = (sA>1)?c2:k_start;
    k_start = (sA>2)?c3:k_start; k_start = (sA>3)?c4:k_start;
    k_start = (sA>4)?c5:k_start; k_start = (sA>5)?c6:k_start;
    k_start = (sA>6)?c7:k_start;
    int k_end = c1;
    k_end = (sB>0)?c2:k_end; k_end = (sB>1)?c3:k_end;
    k_end = (sB>2)?c4:k_end; k_end = (sB>3)?c5:k_end;
    k_end = (sB>4)?c6:k_end; k_end = (sB>5)?c7:k_end;
    k_end = (sB>6)?c8:k_end;

    // this lane's q (S^T: q = l15 column), its segment id
    const int qrow = qbase + l15;
    const int segq = (qrow>=q1)+(qrow>=q2)+(qrow>=q3)+(qrow>=q4)
                   + (qrow>=q5)+(qrow>=q6)+(qrow>=q7);

    // Q B-fragment, pre-scaled by (1/8)*log2(e); C-init -8*log2(e) -> bare exp2
    const float SC = 0.125f * 1.44269504f;
    const float* qp = Q + ((size_t)qrow * H + h) * D + quad * 8;
    short8v aQ0, aQ1;
    {
        float4 a = *(const float4*)(qp);
        float4 b = *(const float4*)(qp + 4);
        float4 c = *(const float4*)(qp + 32);
        float4 e = *(const float4*)(qp + 36);
        aQ0[0]=f2bf(a.x*SC); aQ0[1]=f2bf(a.y*SC); aQ0[2]=f2bf(a.z*SC); aQ0[3]=f2bf(a.w*SC);
        aQ0[4]=f2bf(b.x*SC); aQ0[5]=f2bf(b.y*SC); aQ0[6]=f2bf(b.z*SC); aQ0[7]=f2bf(b.w*SC);
        aQ1[0]=f2bf(c.x*SC); aQ1[1]=f2bf(c.y*SC); aQ1[2]=f2bf(c.z*SC); aQ1[3]=f2bf(c.w*SC);
        aQ1[4]=f2bf(e.x*SC); aQ1[5]=f2bf(e.y*SC); aQ1[6]=f2bf(e.z*SC); aQ1[7]=f2bf(e.w*SC);
    }

    const short* Kbh = Kb + (size_t)h * T * D;
    const short* Vbh = Vb + (size_t)h * D * T;

    floatx4 o[4];
    #pragma unroll
    for (int nt = 0; nt < 4; ++nt) o[nt] = (floatx4){0.f, 0.f, 0.f, 0.f};
    float l_r = 0.f;

    const float C0 = -11.54156032f;   // -8 * log2(e)
    const int kc0 = k_start & ~(BK - 1);
    const int nch = (k_end - kc0 + BK - 1) >> 6;

    // two K fragment sets (even/odd chunks), one V set, one seg set
    short8v kA[8], kB[8], vC[8];
    int4 sg[4];

    const short* kpb = Kbh + (size_t)(kc0 + l15) * D + quad * 8;
    const short* vpb = Vbh + (size_t)l15 * T + kc0 + quad * 8;
    const int*   spb = segArr + kc0 + quad * 4;

    auto LOADK = [&](short8v* dst, int ic_) {
        const short* kp = kpb + (size_t)ic_ * BK * D;
        #pragma unroll
        for (int nt = 0; nt < 4; ++nt) {
            dst[nt * 2]     = *(const short8v*)(kp + nt * 16 * D);
            dst[nt * 2 + 1] = *(const short8v*)(kp + nt * 16 * D + 32);
        }
    };
    auto LOADV = [&](int ic_) {
        const short* vp = vpb + ic_ * BK;
        #pragma unroll
        for (int nt = 0; nt < 4; ++nt) {
            vC[nt * 2]     = *(const short8v*)(vp + (size_t)nt * 16 * T);
            vC[nt * 2 + 1] = *(const short8v*)(vp + (size_t)nt * 16 * T + 32);
        }
    };
    auto LOADS = [&](int ic_) {
        const int* sp = spb + ic_ * BK;
        #pragma unroll
        for (int nt = 0; nt < 4; ++nt)
            sg[nt] = *(const int4*)(sp + nt * 16);
    };

    // prologue: chunk 0 -> K-set A, V, segs
    if (nch > 0) { LOADK(kA, 0); LOADV(0); LOADS(0); }

    for (int ic = 0; ic < nch; ++ic) {
        const bool more = (ic + 1) < nch;
        short8v* kc_cur = (ic & 1) ? kB : kA;
        short8v* kc_nxt = (ic & 1) ? kA : kB;

        // issue next chunk's K loads first: a full iteration of cover
        if (more) LOADK(kc_nxt, ic + 1);

        // ---- S^T = K (Q*log2e)^T - 8*log2e ----
        floatx4 sacc[4];
        #pragma unroll
        for (int nt = 0; nt < 4; ++nt) {
            sacc[nt] = (floatx4){C0, C0, C0, C0};
            sacc[nt] = __builtin_amdgcn_mfma_f32_16x16x32_bf16(kc_cur[nt * 2],     aQ0, sacc[nt], 0, 0, 0);
            sacc[nt] = __builtin_amdgcn_mfma_f32_16x16x32_bf16(kc_cur[nt * 2 + 1], aQ1, sacc[nt], 0, 0, 0);
        }

        // ---- mask + exp2 + pack to PV B-operand, all in registers ----
        unsigned pk[8];
        #pragma unroll
        for (int nt = 0; nt < 4; ++nt) {
            const int4 s = sg[nt];
            float p0 = (s.x == segq) ? __builtin_amdgcn_exp2f(sacc[nt][0]) : 0.f;
            float p1 = (s.y == segq) ? __builtin_amdgcn_exp2f(sacc[nt][1]) : 0.f;
            float p2 = (s.z == segq) ? __builtin_amdgcn_exp2f(sacc[nt][2]) : 0.f;
            float p3 = (s.w == segq) ? __builtin_amdgcn_exp2f(sacc[nt][3]) : 0.f;
            l_r += (p0 + p1) + (p2 + p3);
            pk[nt * 2]     = cvtpk(p0, p1);
            pk[nt * 2 + 1] = cvtpk(p2, p3);
        }
        // segs consumed -> issue next chunk's seg loads
        if (more) LOADS(ic + 1);

        union BP { unsigned u[4]; short8v s; };
        BP blo, bhi;
        blo.u[0] = pk[0]; blo.u[1] = pk[1]; blo.u[2] = pk[2]; blo.u[3] = pk[3];
        bhi.u[0] = pk[4]; bhi.u[1] = pk[5]; bhi.u[2] = pk[6]; bhi.u[3] = pk[7];

        // ---- O^T += V^T P^T (Vb columns pre-permuted to match bP k-slots) ----
        #pragma unroll
        for (int ntd = 0; ntd < 4; ++ntd) {
            o[ntd] = __builtin_amdgcn_mfma_f32_16x16x32_bf16(vC[ntd * 2],     blo.s, o[ntd], 0, 0, 0);
            o[ntd] = __builtin_amdgcn_mfma_f32_16x16x32_bf16(vC[ntd * 2 + 1], bhi.s, o[ntd], 0, 0, 0);
        }
        // V consumed -> issue next chunk's V loads (cover = next QK+softmax)
        if (more) LOADV(ic + 1);
    }

    // ---- epilogue: l reduce over quads; O^T -> O via wave-private scratch ----
    l_r += __shfl_xor(l_r, 16);
    l_r += __shfl_xor(l_r, 32);
    const float linv = 1.0f / l_r;

    #pragma unroll
    for (int ntd = 0; ntd < 4; ++ntd)
        #pragma unroll
        for (int r = 0; r < 4; ++r)
            fsc[l15][ntd * 16 + quad * 4 + r] = o[ntd][r] * linv;

    // same-wave LDS roundtrip (in-order within the wave) -> coalesced stores
    const int rr = lane >> 2;
    const int dc = (lane & 3) << 4;
    const float* fr = &fsc[rr][dc];
    float* op = O + ((size_t)(qbase + rr) * H + h) * D + dc;
    #pragma unroll
    for (int i = 0; i < 4; ++i)
        *(float4*)(op + 4 * i) = *(const float4*)(fr + 4 * i);
}

// ---- fallback (self-contained, any T) -------------------------------------
__global__ __launch_bounds__(256)
void varlen_attn_fb(const float* __restrict__ Q, const float* __restrict__ K,
                    const float* __restrict__ V, const int* __restrict__ cuq,
                    const int* __restrict__ cuk, float* __restrict__ O, int T)
{
    __shared__ short sK[BK][LDKP];
    __shared__ short sVT[D][BK + 8];
    __shared__ short sP[4][16][BK + 8];
    __shared__ int   sSegK[BK];
    __shared__ int   sCuQ[NSEG + 1], sCuK[NSEG + 1];

    const int tid  = threadIdx.x;
    const int lane = tid & 63;
    const int w    = tid >> 6;
    const int quad = lane >> 4;
    const int l15  = lane & 15;
    const int h    = blockIdx.x % H;
    const int t0   = (blockIdx.x / H) * 64;

    if (tid <= NSEG) { sCuQ[tid] = cuq[tid]; sCuK[tid] = cuk[tid]; }
    __syncthreads();

    int qrow = t0 + 16 * w + l15; if (qrow >= T) qrow = T - 1;
    const float* qp = Q + ((size_t)qrow * H + h) * D + quad * 8;
    short8v aQ0, aQ1;
    {
        float4 a = *(const float4*)(qp);
        float4 b = *(const float4*)(qp + 4);
        float4 c = *(const float4*)(qp + 32);
        float4 e = *(const float4*)(qp + 36);
        aQ0[0]=f2bf(a.x*0.125f); aQ0[1]=f2bf(a.y*0.125f);
        aQ0[2]=f2bf(a.z*0.125f); aQ0[3]=f2bf(a.w*0.125f);
        aQ0[4]=f2bf(b.x*0.125f); aQ0[5]=f2bf(b.y*0.125f);
        aQ0[6]=f2bf(b.z*0.125f); aQ0[7]=f2bf(b.w*0.125f);
        aQ1[0]=f2bf(c.x*0.125f); aQ1[1]=f2bf(c.y*0.125f);
        aQ1[2]=f2bf(c.z*0.125f); aQ1[3]=f2bf(c.w*0.125f);
        aQ1[4]=f2bf(e.x*0.125f); aQ1[5]=f2bf(e.y*0.125f);
        aQ1[6]=f2bf(e.z*0.125f); aQ1[7]=f2bf(e.w*0.125f);
    }

    int segq[4];
    #pragma unroll
    for (int r = 0; r < 4; ++r) {
        int t = t0 + 16 * w + quad * 4 + r; if (t >= T) t = T - 1;
        int s = 0;
        while (s < NSEG - 1 && t >= sCuQ[s + 1]) ++s;
        segq[r] = s;
    }
    int k_start, k_end;
    {
        int tA = t0; if (tA >= T) tA = T - 1;
        int tB = t0 + 63; if (tB >= T) tB = T - 1;
        int sA = 0; while (sA < NSEG - 1 && tA >= sCuQ[sA + 1]) ++sA;
        int sB = 0; while (sB < NSEG - 1 && tB >= sCuQ[sB + 1]) ++sB;
        k_start = sCuK[sA];
        k_end   = sCuK[sB + 1];
    }

    floatx4 o[4];
    #pragma unroll
    for (int nt = 0; nt < 4; ++nt) o[nt] = (floatx4){0.f, 0.f, 0.f, 0.f};
    float l_r[4] = {0.f, 0.f, 0.f, 0.f};

    for (int kc = k_start; kc < k_end; kc += BK) {
        __syncthreads();
        for (int i = tid; i < BK * D / 4; i += 256) {
            int k = i >> 4;
            int c = (i & 15) << 2;
            int kt = kc + k;
            float4 kv = {0,0,0,0}, vv = {0,0,0,0};
            if (kt < k_end) {
                kv = *(const float4*)&K[((size_t)kt * H + h) * D + c];
                vv = *(const float4*)&V[((size_t)kt * H + h) * D + c];
            }
            short4v ks;
            ks.x=f2bf(kv.x); ks.y=f2bf(kv.y); ks.z=f2bf(kv.z); ks.w=f2bf(kv.w);
            *(short4v*)&sK[k][c] = ks;
            sVT[c+0][k]=f2bf(vv.x); sVT[c+1][k]=f2bf(vv.y);
            sVT[c+2][k]=f2bf(vv.z); sVT[c+3][k]=f2bf(vv.w);
        }
        if (tid < BK) {
            int kt = kc + tid;
            int s = -1;
            if (kt < k_end) { s = 0; while (s < NSEG - 1 && kt >= sCuK[s + 1]) ++s; }
            sSegK[tid] = s;
        }
        __syncthreads();

        floatx4 sacc[4];
        #pragma unroll
        for (int nt = 0; nt < 4; ++nt) {
            sacc[nt] = (floatx4){-8.f, -8.f, -8.f, -8.f};
            short8v b0 = *(const short8v*)&sK[nt * 16 + l15][quad * 8];
            short8v b1 = *(const short8v*)&sK[nt * 16 + l15][32 + quad * 8];
            sacc[nt] = __builtin_amdgcn_mfma_f32_16x16x32_bf16(aQ0, b0, sacc[nt], 0, 0, 0);
            sacc[nt] = __builtin_amdgcn_mfma_f32_16x16x32_bf16(aQ1, b1, sacc[nt], 0, 0, 0);
        }
        #pragma unroll
        for (int nt = 0; nt < 4; ++nt) {
            int segk = sSegK[nt * 16 + l15];
            #pragma unroll
            for (int r = 0; r < 4; ++r) {
                float sc = (segk == segq[r]) ? sacc[nt][r] : -1e30f;
                float p  = __expf(sc);
                l_r[r] += p;
                sP[w][quad * 4 + r][nt * 16 + l15] = f2bf(p);
            }
        }
        short8v aP0 = *(const short8v*)&sP[w][l15][quad * 8];
        short8v aP1 = *(const short8v*)&sP[w][l15][32 + quad * 8];
        #pragma unroll
        for (int nt = 0; nt < 4; ++nt) {
            short8v b0 = *(const short8v*)&sVT[nt * 16 + l15][quad * 8];
            short8v b1 = *(const short8v*)&sVT[nt * 16 + l15][32 + quad * 8];
            o[nt] = __builtin_amdgcn_mfma_f32_16x16x32_bf16(aP0, b0, o[nt], 0, 0, 0);
            o[nt] = __builtin_amdgcn_mfma_f32_16x16x32_bf16(aP1, b1, o[nt], 0, 0, 0);
        }
    }

    #pragma unroll
    for (int off = 1; off < 16; off <<= 1)
        #pragma unroll
        for (int r = 0; r < 4; ++r)
            l_r[r] += __shfl_xor(l_r[r], off);

    #pragma unroll
    for (int r = 0; r < 4; ++r) {
        int trow = t0 + 16 * w + quad * 4 + r;
        if (trow < T) {
            float linv = 1.0f / l_r[r];
            float* op = O + ((size_t)trow * H + h) * D + l15;
            #pragma unroll
            for (int nt = 0; nt < 4; ++nt)
                op[nt * 16] = o[nt][r] * linv;
        }
    }
}

extern "C" void kernel_launch(void* const* d_in, const int* in_sizes, int n_in,
                              void* d_out, int out_size, void* d_ws, size_t ws_size,
                              hipStream_t stream) {
    const float* Q = (const float*)d_in[0];
    const float* K = (const float*)d_in[1];
    const float* V = (const float*)d_in[2];
    const int* cuq = (const int*)d_in[3];
    const int* cuk = (const int*)d_in[4];
    float* O = (float*)d_out;
    (void)n_in; (void)out_size;

    int T = in_sizes[0] / (H * D);
    int nQB = T >> 6;
    size_t need = (size_t)2 * H * T * D * sizeof(short) + (size_t)T * sizeof(int);

    if (ws_size >= need && (T & 63) == 0) {
        short* Kb = (short*)d_ws;
        short* Vb = Kb + (size_t)H * T * D;
        int* segArr = (int*)(Vb + (size_t)H * T * D);
        hipLaunchKernelGGL(prepass_kv, dim3(nQB * H), dim3(256), 0, stream,
                           K, V, cuk, Kb, Vb, segArr, T);
        hipLaunchKernelGGL(varlen_attn13, dim3((T >> 4) * H), dim3(64), 0, stream,
                           Q, Kb, Vb, segArr, cuq, cuk, O, T);
    } else {
        int nQT = (T + 63) / 64;
        hipLaunchKernelGGL(varlen_attn_fb, dim3(nQT * H), dim3(256), 0, stream,
                           Q, K, V, cuq, cuk, O, T);
    }
}

// Round 9
// 123.788 us; speedup vs baseline: 1.3999x; 1.3999x over previous
//
#include <hip/hip_runtime.h>

// VarlenAttention MI355X — round 14: 2-CHUNK IN-WAVE INTERLEAVE (pair staging).
// r13 post-mortem: global-direct dead (92us twice, VGPR-independent — per-wave
// L2 chains can't be covered at 3 waves/SIMD). r11 staged (attn ~39us) is the
// base. Accounting: ~975 serial cyc/wave-chunk vs ~600 issue -> latency-bound
// with only 3 independent streams/SIMD. This round: stage a 128-key PAIR per
// block (sK[128][64] + sVT[64][128] = 32KB, same footprint, 3 blocks/CU) and
// compute TWO independent chunk chains per iteration -> ~6 streams/SIMD,
// barrier rate unchanged (2/pair = 1 per 64 keys), next-pair register
// prefetch covered by a full pair-compute. OOB pair tails masked via 64
// padded segArr entries (0x7FFF) + clamped loads. Everything else = r11
// (swapped MFMA, pi-permuted Vb, exp2 softmax, XCD-aligned placement).
constexpr int NSEG = 8;
constexpr int H    = 16;
constexpr int D    = 64;
constexpr int BK   = 64;
constexpr int LDKP = D + 8;   // prepass/fallback padded layout

typedef __attribute__((ext_vector_type(8))) short short8v;
typedef __attribute__((ext_vector_type(4))) short short4v;
typedef __attribute__((ext_vector_type(4))) float floatx4;

__device__ inline short f2bf(float f) {  // RNE fp32 -> bf16
    union { float f; unsigned u; } x; x.f = f;
    unsigned r = x.u + 0x7FFFu + ((x.u >> 16) & 1u);
    return (short)(r >> 16);
}

__device__ inline unsigned cvtpk(float lo, float hi) {  // 2 f32 -> packed bf16x2
    unsigned r;
    asm("v_cvt_pk_bf16_f32 %0, %1, %2" : "=v"(r) : "v"(lo), "v"(hi));
    return r;
}

// ---- pre-pass: Kb[h][t][d], Vb[h][d][pi(t)], segArr[t] (+64 pad) ----------
// blockIdx = chunk*H + h -> writer XCD == reader XCD == h%8 (r11).
// V column permutation per 8-key group t8: first 4 keys at c0, last 4 at
// c0+8, c0 = (t8&32)|((t8&8)<<1)|((t8&16)>>2)  (validated r9/r10).
__global__ __launch_bounds__(256)
void prepass_kv(const float* __restrict__ K, const float* __restrict__ V,
                const int* __restrict__ cuk,
                short* __restrict__ Kb, short* __restrict__ Vb,
                int* __restrict__ segArr, int T)
{
    __shared__ short sVT[D][LDKP];
    const int tid = threadIdx.x;
    const int h  = blockIdx.x & (H - 1);
    const int t0 = (blockIdx.x >> 4) << 6;
    #pragma unroll
    for (int it = 0; it < 2; ++it) {
        int s  = tid + it * 256;
        int tl = s >> 3;
        int d8 = (s & 7) << 3;
        int t  = t0 + tl;
        const float* kp = K + ((size_t)t * H + h) * D + d8;
        float4 a = *(const float4*)kp;
        float4 b = *(const float4*)(kp + 4);
        short8v ks;
        ks[0]=f2bf(a.x); ks[1]=f2bf(a.y); ks[2]=f2bf(a.z); ks[3]=f2bf(a.w);
        ks[4]=f2bf(b.x); ks[5]=f2bf(b.y); ks[6]=f2bf(b.z); ks[7]=f2bf(b.w);
        *(short8v*)&Kb[((size_t)h * T + t) * D + d8] = ks;
        const float* vp = V + ((size_t)t * H + h) * D + d8;
        float4 c = *(const float4*)vp;
        float4 e = *(const float4*)(vp + 4);
        sVT[d8+0][tl]=f2bf(c.x); sVT[d8+1][tl]=f2bf(c.y);
        sVT[d8+2][tl]=f2bf(c.z); sVT[d8+3][tl]=f2bf(c.w);
        sVT[d8+4][tl]=f2bf(e.x); sVT[d8+5][tl]=f2bf(e.y);
        sVT[d8+6][tl]=f2bf(e.z); sVT[d8+7][tl]=f2bf(e.w);
    }
    if (h == 0 && tid < 64) {
        int t = t0 + tid;
        int s = 0;
        #pragma unroll
        for (int i = 1; i < NSEG; ++i) s += (t >= cuk[i]) ? 1 : 0;
        segArr[t] = s;
        if (t0 == 0) segArr[T + tid] = 0x7FFF;   // pair-tail pad: never matches
    }
    __syncthreads();
    #pragma unroll
    for (int it = 0; it < 2; ++it) {
        int s  = tid + it * 256;
        int d  = s >> 3;
        int t8 = (s & 7) << 3;
        int c0 = (t8 & 32) | ((t8 & 8) << 1) | ((t8 & 16) >> 2);  // pi^-1
        short* vb = &Vb[((size_t)h * D + d) * T + t0];
        *(short4v*)&vb[c0]     = *(const short4v*)&sVT[d][t8];
        *(short4v*)&vb[c0 + 8] = *(const short4v*)&sVT[d][t8 + 4];
    }
}

// ---- main: swapped-MFMA flash, 128-key pair staging, 2 chains/iter --------
__global__ __launch_bounds__(256)
void varlen_attn14(const float* __restrict__ Q,
                   const short* __restrict__ Kb, const short* __restrict__ Vb,
                   const int* __restrict__ segArr,
                   const int* __restrict__ cuq, const int* __restrict__ cuk,
                   float* __restrict__ O, int T)
{
    // 32KB: sK[128][64] + sVT[64][128] (XOR-swizzled slots), single buffer;
    // reused post-loop as the fp32 O-transpose scratch (stride 68).
    __shared__ __align__(16) char smem[32768];
    short* sK = reinterpret_cast<short*>(smem);             // [128*64]
    short* sV = reinterpret_cast<short*>(smem + 16384);     // [64*128]
    float* fsc = reinterpret_cast<float*>(smem);

    const int tid  = threadIdx.x;
    const int lane = tid & 63;
    const int w    = tid >> 6;
    const int quad = lane >> 4;
    const int l15  = lane & 15;
    const int h    = blockIdx.x & (H - 1);
    const int t0   = (blockIdx.x >> 4) << 6;

    const int q1 = cuq[1], q2 = cuq[2], q3 = cuq[3], q4 = cuq[4],
              q5 = cuq[5], q6 = cuq[6], q7 = cuq[7];
    const int c0 = cuk[0], c1 = cuk[1], c2 = cuk[2], c3 = cuk[3], c4 = cuk[4],
              c5 = cuk[5], c6 = cuk[6], c7 = cuk[7], c8 = cuk[8];

    // block k-span (block-uniform)
    int tB = t0 + 63;
    int sA = (t0>=q1)+(t0>=q2)+(t0>=q3)+(t0>=q4)+(t0>=q5)+(t0>=q6)+(t0>=q7);
    int sB = (tB>=q1)+(tB>=q2)+(tB>=q3)+(tB>=q4)+(tB>=q5)+(tB>=q6)+(tB>=q7);
    int k_start = c0;
    k_start = (sA>0)?c1:k_start; k_start = (sA>1)?c2:k_start;
    k_start = (sA>2)?c3:k_start; k_start = (sA>3)?c4:k_start;
    k_start = (sA>4)?c5:k_start; k_start = (sA>5)?c6:k_start;
    k_start = (sA>6)?c7:k_start;
    int k_end = c1;
    k_end = (sB>0)?c2:k_end; k_end = (sB>1)?c3:k_end;
    k_end = (sB>2)?c4:k_end; k_end = (sB>3)?c5:k_end;
    k_end = (sB>4)?c6:k_end; k_end = (sB>5)?c7:k_end;
    k_end = (sB>6)?c8:k_end;

    // this lane's q (S^T: q = l15 column), its segment id
    const int qrow = t0 + 16 * w + l15;
    const int segq = (qrow>=q1)+(qrow>=q2)+(qrow>=q3)+(qrow>=q4)
                   + (qrow>=q5)+(qrow>=q6)+(qrow>=q7);

    // Q B-fragment, pre-scaled by (1/8)*log2(e); C-init -8*log2(e) -> bare exp2
    const float SC = 0.125f * 1.44269504f;
    const float* qp = Q + ((size_t)qrow * H + h) * D + quad * 8;
    short8v aQ0, aQ1;
    {
        float4 a = *(const float4*)(qp);
        float4 b = *(const float4*)(qp + 4);
        float4 c = *(const float4*)(qp + 32);
        float4 e = *(const float4*)(qp + 36);
        aQ0[0]=f2bf(a.x*SC); aQ0[1]=f2bf(a.y*SC); aQ0[2]=f2bf(a.z*SC); aQ0[3]=f2bf(a.w*SC);
        aQ0[4]=f2bf(b.x*SC); aQ0[5]=f2bf(b.y*SC); aQ0[6]=f2bf(b.z*SC); aQ0[7]=f2bf(b.w*SC);
        aQ1[0]=f2bf(c.x*SC); aQ1[1]=f2bf(c.y*SC); aQ1[2]=f2bf(c.z*SC); aQ1[3]=f2bf(c.w*SC);
        aQ1[4]=f2bf(e.x*SC); aQ1[5]=f2bf(e.y*SC); aQ1[6]=f2bf(e.z*SC); aQ1[7]=f2bf(e.w*SC);
    }

    const short* Kbh = Kb + (size_t)h * T * D;
    const short* Vbh = Vb + (size_t)h * D * T;
    const int key0 = tid >> 3;                         // 0..31
    const int e8   = (tid & 7) << 3;                   // 0..56
    const int slA  = (((tid & 7) ^ (key0 & 7)) << 3);  // swizzled write slot
    const int sw3  = (l15 & 7) << 3;                   // swizzled read offset

    // next-pair staging registers (4 K + 4 V short8v = 32 VGPR)
    short8v rk0, rk1, rk2, rk3, rv0, rv1, rv2, rv3;

    auto LOADP = [&](int kc_) {   // register prefetch of pair at kc_ (128 keys)
        const bool hi = (kc_ + 64) < T;           // block-uniform
        const int kc2 = hi ? kc_ + 64 : kc_;      // clamped (garbage, seg-masked)
        rk0 = *(const short8v*)(Kbh + (size_t)(kc_ + key0)      * D + e8);
        rk1 = *(const short8v*)(Kbh + (size_t)(kc_ + 32 + key0) * D + e8);
        rk2 = *(const short8v*)(Kbh + (size_t)(kc2 + key0)      * D + e8);
        rk3 = *(const short8v*)(Kbh + (size_t)(kc2 + 32 + key0) * D + e8);
        rv0 = *(const short8v*)(Vbh + (size_t)key0        * T + kc_ + e8);
        rv1 = *(const short8v*)(Vbh + (size_t)(32 + key0) * T + kc_ + e8);
        rv2 = *(const short8v*)(Vbh + (size_t)key0        * T + kc2 + e8);
        rv3 = *(const short8v*)(Vbh + (size_t)(32 + key0) * T + kc2 + e8);
    };
    auto WRITEP = [&]() {         // regs -> swizzled LDS (single buffer)
        *(short8v*)&sK[( key0      ) * D + slA] = rk0;   // rows keep row&7
        *(short8v*)&sK[( key0 + 32 ) * D + slA] = rk1;
        *(short8v*)&sK[( key0 + 64 ) * D + slA] = rk2;
        *(short8v*)&sK[( key0 + 96 ) * D + slA] = rk3;
        *(short8v*)&sV[  key0       * 128 + slA]      = rv0;
        *(short8v*)&sV[ (key0 + 32) * 128 + slA]      = rv1;
        *(short8v*)&sV[  key0       * 128 + 64 + slA] = rv2;
        *(short8v*)&sV[ (key0 + 32) * 128 + 64 + slA] = rv3;
    };

    floatx4 o[4];
    #pragma unroll
    for (int nt = 0; nt < 4; ++nt) o[nt] = (floatx4){0.f, 0.f, 0.f, 0.f};
    float l_r = 0.f;

    const float C0 = -11.54156032f;   // -8 * log2(e)
    const int kc0 = k_start & ~127;                     // pair-aligned
    const int nkp = (k_end - kc0 + 127) >> 7;           // pairs

    LOADP(kc0);
    WRITEP();

    for (int ip = 0; ip < nkp; ++ip) {
        __syncthreads();                         // pair ip visible in LDS
        const int kc   = kc0 + ip * 128;
        const int kcn  = kc + 128;
        const bool more = kcn < k_end;           // block-uniform
        if (more) LOADP(kcn);                    // covered by full pair compute

        // ---- QK^T, both chunks (independent chains) ----
        floatx4 s0[4], s1[4];
        #pragma unroll
        for (int nt = 0; nt < 4; ++nt) {
            const short* kr = &sK[(nt * 16 + l15) * D];
            short8v a0 = *(const short8v*)(kr + (( quad      << 3) ^ sw3));
            short8v a1 = *(const short8v*)(kr + (((quad + 4) << 3) ^ sw3));
            s0[nt] = (floatx4){C0, C0, C0, C0};
            s0[nt] = __builtin_amdgcn_mfma_f32_16x16x32_bf16(a0, aQ0, s0[nt], 0, 0, 0);
            s0[nt] = __builtin_amdgcn_mfma_f32_16x16x32_bf16(a1, aQ1, s0[nt], 0, 0, 0);
        }
        #pragma unroll
        for (int nt = 0; nt < 4; ++nt) {
            const short* kr = &sK[(64 + nt * 16 + l15) * D];
            short8v a0 = *(const short8v*)(kr + (( quad      << 3) ^ sw3));
            short8v a1 = *(const short8v*)(kr + (((quad + 4) << 3) ^ sw3));
            s1[nt] = (floatx4){C0, C0, C0, C0};
            s1[nt] = __builtin_amdgcn_mfma_f32_16x16x32_bf16(a0, aQ0, s1[nt], 0, 0, 0);
            s1[nt] = __builtin_amdgcn_mfma_f32_16x16x32_bf16(a1, aQ1, s1[nt], 0, 0, 0);
        }

        // ---- mask + exp2 + pack, both chunks (segs: L2-hot small loads) ----
        unsigned pk0[8], pk1[8];
        #pragma unroll
        for (int nt = 0; nt < 4; ++nt) {
            int4 s = *(const int4*)(segArr + kc + nt * 16 + quad * 4);
            float p0 = (s.x == segq) ? __builtin_amdgcn_exp2f(s0[nt][0]) : 0.f;
            float p1 = (s.y == segq) ? __builtin_amdgcn_exp2f(s0[nt][1]) : 0.f;
            float p2 = (s.z == segq) ? __builtin_amdgcn_exp2f(s0[nt][2]) : 0.f;
            float p3 = (s.w == segq) ? __builtin_amdgcn_exp2f(s0[nt][3]) : 0.f;
            l_r += (p0 + p1) + (p2 + p3);
            pk0[nt * 2]     = cvtpk(p0, p1);
            pk0[nt * 2 + 1] = cvtpk(p2, p3);
        }
        #pragma unroll
        for (int nt = 0; nt < 4; ++nt) {
            int4 s = *(const int4*)(segArr + kc + 64 + nt * 16 + quad * 4);
            float p0 = (s.x == segq) ? __builtin_amdgcn_exp2f(s1[nt][0]) : 0.f;
            float p1 = (s.y == segq) ? __builtin_amdgcn_exp2f(s1[nt][1]) : 0.f;
            float p2 = (s.z == segq) ? __builtin_amdgcn_exp2f(s1[nt][2]) : 0.f;
            float p3 = (s.w == segq) ? __builtin_amdgcn_exp2f(s1[nt][3]) : 0.f;
            l_r += (p0 + p1) + (p2 + p3);
            pk1[nt * 2]     = cvtpk(p0, p1);
            pk1[nt * 2 + 1] = cvtpk(p2, p3);
        }
        union BP { unsigned u[4]; short8v s; };
        BP b0lo, b0hi, b1lo, b1hi;
        b0lo.u[0]=pk0[0]; b0lo.u[1]=pk0[1]; b0lo.u[2]=pk0[2]; b0lo.u[3]=pk0[3];
        b0hi.u[0]=pk0[4]; b0hi.u[1]=pk0[5]; b0hi.u[2]=pk0[6]; b0hi.u[3]=pk0[7];
        b1lo.u[0]=pk1[0]; b1lo.u[1]=pk1[1]; b1lo.u[2]=pk1[2]; b1lo.u[3]=pk1[3];
        b1hi.u[0]=pk1[4]; b1hi.u[1]=pk1[5]; b1hi.u[2]=pk1[6]; b1hi.u[3]=pk1[7];

        // ---- O^T += V^T P^T, both chunks ----
        #pragma unroll
        for (int ntd = 0; ntd < 4; ++ntd) {
            const short* vr = &sV[(ntd * 16 + l15) * 128];
            short8v v0 = *(const short8v*)(vr + (( quad      << 3) ^ sw3));
            short8v v1 = *(const short8v*)(vr + (((quad + 4) << 3) ^ sw3));
            o[ntd] = __builtin_amdgcn_mfma_f32_16x16x32_bf16(v0, b0lo.s, o[ntd], 0, 0, 0);
            o[ntd] = __builtin_amdgcn_mfma_f32_16x16x32_bf16(v1, b0hi.s, o[ntd], 0, 0, 0);
        }
        #pragma unroll
        for (int ntd = 0; ntd < 4; ++ntd) {
            const short* vr = &sV[(ntd * 16 + l15) * 128 + 64];
            short8v v0 = *(const short8v*)(vr + (( quad      << 3) ^ sw3));
            short8v v1 = *(const short8v*)(vr + (((quad + 4) << 3) ^ sw3));
            o[ntd] = __builtin_amdgcn_mfma_f32_16x16x32_bf16(v0, b1lo.s, o[ntd], 0, 0, 0);
            o[ntd] = __builtin_amdgcn_mfma_f32_16x16x32_bf16(v1, b1hi.s, o[ntd], 0, 0, 0);
        }

        __syncthreads();                         // all reads of pair ip done
        if (more) WRITEP();                      // stage pair ip+1
    }

    // ---- epilogue: l reduce over quads; O^T -> O via LDS scratch ----
    l_r += __shfl_xor(l_r, 16);
    l_r += __shfl_xor(l_r, 32);
    const float linv = 1.0f / l_r;

    __syncthreads();              // safe to reuse smem as fp32 scratch
    #pragma unroll
    for (int ntd = 0; ntd < 4; ++ntd)
        #pragma unroll
        for (int r = 0; r < 4; ++r)
            fsc[(16 * w + l15) * 68 + ntd * 16 + quad * 4 + r] = o[ntd][r] * linv;

    // same-wave LDS roundtrip (wave-private rows) -> coalesced float4 stores
    const int rr = lane >> 2;
    const int dc = (lane & 3) << 4;
    const float* fr = &fsc[(16 * w + rr) * 68 + dc];
    float* op = O + ((size_t)(t0 + 16 * w + rr) * H + h) * D + dc;
    #pragma unroll
    for (int i = 0; i < 4; ++i)
        *(float4*)(op + 4 * i) = *(const float4*)(fr + 4 * i);
}

// ---- fallback (self-contained, any T) -------------------------------------
__global__ __launch_bounds__(256)
void varlen_attn_fb(const float* __restrict__ Q, const float* __restrict__ K,
                    const float* __restrict__ V, const int* __restrict__ cuq,
                    const int* __restrict__ cuk, float* __restrict__ O, int T)
{
    __shared__ short sK[BK][LDKP];
    __shared__ short sVT[D][BK + 8];
    __shared__ short sP[4][16][BK + 8];
    __shared__ int   sSegK[BK];
    __shared__ int   sCuQ[NSEG + 1], sCuK[NSEG + 1];

    const int tid  = threadIdx.x;
    const int lane = tid & 63;
    const int w    = tid >> 6;
    const int quad = lane >> 4;
    const int l15  = lane & 15;
    const int h    = blockIdx.x % H;
    const int t0   = (blockIdx.x / H) * 64;

    if (tid <= NSEG) { sCuQ[tid] = cuq[tid]; sCuK[tid] = cuk[tid]; }
    __syncthreads();

    int qrow = t0 + 16 * w + l15; if (qrow >= T) qrow = T - 1;
    const float* qp = Q + ((size_t)qrow * H + h) * D + quad * 8;
    short8v aQ0, aQ1;
    {
        float4 a = *(const float4*)(qp);
        float4 b = *(const float4*)(qp + 4);
        float4 c = *(const float4*)(qp + 32);
        float4 e = *(const float4*)(qp + 36);
        aQ0[0]=f2bf(a.x*0.125f); aQ0[1]=f2bf(a.y*0.125f);
        aQ0[2]=f2bf(a.z*0.125f); aQ0[3]=f2bf(a.w*0.125f);
        aQ0[4]=f2bf(b.x*0.125f); aQ0[5]=f2bf(b.y*0.125f);
        aQ0[6]=f2bf(b.z*0.125f); aQ0[7]=f2bf(b.w*0.125f);
        aQ1[0]=f2bf(c.x*0.125f); aQ1[1]=f2bf(c.y*0.125f);
        aQ1[2]=f2bf(c.z*0.125f); aQ1[3]=f2bf(c.w*0.125f);
        aQ1[4]=f2bf(e.x*0.125f); aQ1[5]=f2bf(e.y*0.125f);
        aQ1[6]=f2bf(e.z*0.125f); aQ1[7]=f2bf(e.w*0.125f);
    }

    int segq[4];
    #pragma unroll
    for (int r = 0; r < 4; ++r) {
        int t = t0 + 16 * w + quad * 4 + r; if (t >= T) t = T - 1;
        int s = 0;
        while (s < NSEG - 1 && t >= sCuQ[s + 1]) ++s;
        segq[r] = s;
    }
    int k_start, k_end;
    {
        int tA = t0; if (tA >= T) tA = T - 1;
        int tB = t0 + 63; if (tB >= T) tB = T - 1;
        int sA = 0; while (sA < NSEG - 1 && tA >= sCuQ[sA + 1]) ++sA;
        int sB = 0; while (sB < NSEG - 1 && tB >= sCuQ[sB + 1]) ++sB;
        k_start = sCuK[sA];
        k_end   = sCuK[sB + 1];
    }

    floatx4 o[4];
    #pragma unroll
    for (int nt = 0; nt < 4; ++nt) o[nt] = (floatx4){0.f, 0.f, 0.f, 0.f};
    float l_r[4] = {0.f, 0.f, 0.f, 0.f};

    for (int kc = k_start; kc < k_end; kc += BK) {
        __syncthreads();
        for (int i = tid; i < BK * D / 4; i += 256) {
            int k = i >> 4;
            int c = (i & 15) << 2;
            int kt = kc + k;
            float4 kv = {0,0,0,0}, vv = {0,0,0,0};
            if (kt < k_end) {
                kv = *(const float4*)&K[((size_t)kt * H + h) * D + c];
                vv = *(const float4*)&V[((size_t)kt * H + h) * D + c];
            }
            short4v ks;
            ks.x=f2bf(kv.x); ks.y=f2bf(kv.y); ks.z=f2bf(kv.z); ks.w=f2bf(kv.w);
            *(short4v*)&sK[k][c] = ks;
            sVT[c+0][k]=f2bf(vv.x); sVT[c+1][k]=f2bf(vv.y);
            sVT[c+2][k]=f2bf(vv.z); sVT[c+3][k]=f2bf(vv.w);
        }
        if (tid < BK) {
            int kt = kc + tid;
            int s = -1;
            if (kt < k_end) { s = 0; while (s < NSEG - 1 && kt >= sCuK[s + 1]) ++s; }
            sSegK[tid] = s;
        }
        __syncthreads();

        floatx4 sacc[4];
        #pragma unroll
        for (int nt = 0; nt < 4; ++nt) {
            sacc[nt] = (floatx4){-8.f, -8.f, -8.f, -8.f};
            short8v b0 = *(const short8v*)&sK[nt * 16 + l15][quad * 8];
            short8v b1 = *(const short8v*)&sK[nt * 16 + l15][32 + quad * 8];
            sacc[nt] = __builtin_amdgcn_mfma_f32_16x16x32_bf16(aQ0, b0, sacc[nt], 0, 0, 0);
            sacc[nt] = __builtin_amdgcn_mfma_f32_16x16x32_bf16(aQ1, b1, sacc[nt], 0, 0, 0);
        }
        #pragma unroll
        for (int nt = 0; nt < 4; ++nt) {
            int segk = sSegK[nt * 16 + l15];
            #pragma unroll
            for (int r = 0; r < 4; ++r) {
                float sc = (segk == segq[r]) ? sacc[nt][r] : -1e30f;
                float p  = __expf(sc);
                l_r[r] += p;
                sP[w][quad * 4 + r][nt * 16 + l15] = f2bf(p);
            }
        }
        short8v aP0 = *(const short8v*)&sP[w][l15][quad * 8];
        short8v aP1 = *(const short8v*)&sP[w][l15][32 + quad * 8];
        #pragma unroll
        for (int nt = 0; nt < 4; ++nt) {
            short8v b0 = *(const short8v*)&sVT[nt * 16 + l15][quad * 8];
            short8v b1 = *(const short8v*)&sVT[nt * 16 + l15][32 + quad * 8];
            o[nt] = __builtin_amdgcn_mfma_f32_16x16x32_bf16(aP0, b0, o[nt], 0, 0, 0);
            o[nt] = __builtin_amdgcn_mfma_f32_16x16x32_bf16(aP1, b1, o[nt], 0, 0, 0);
        }
    }

    #pragma unroll
    for (int off = 1; off < 16; off <<= 1)
        #pragma unroll
        for (int r = 0; r < 4; ++r)
            l_r[r] += __shfl_xor(l_r[r], off);

    #pragma unroll
    for (int r = 0; r < 4; ++r) {
        int trow = t0 + 16 * w + quad * 4 + r;
        if (trow < T) {
            float linv = 1.0f / l_r[r];
            float* op = O + ((size_t)trow * H + h) * D + l15;
            #pragma unroll
            for (int nt = 0; nt < 4; ++nt)
                op[nt * 16] = o[nt][r] * linv;
        }
    }
}

extern "C" void kernel_launch(void* const* d_in, const int* in_sizes, int n_in,
                              void* d_out, int out_size, void* d_ws, size_t ws_size,
                              hipStream_t stream) {
    const float* Q = (const float*)d_in[0];
    const float* K = (const float*)d_in[1];
    const float* V = (const float*)d_in[2];
    const int* cuq = (const int*)d_in[3];
    const int* cuk = (const int*)d_in[4];
    float* O = (float*)d_out;
    (void)n_in; (void)out_size;

    int T = in_sizes[0] / (H * D);
    int nQB = T >> 6;
    size_t need = (size_t)2 * H * T * D * sizeof(short) + (size_t)(T + 64) * sizeof(int);

    if (ws_size >= need && (T & 63) == 0) {
        short* Kb = (short*)d_ws;
        short* Vb = Kb + (size_t)H * T * D;
        int* segArr = (int*)(Vb + (size_t)H * T * D);
        hipLaunchKernelGGL(prepass_kv, dim3(nQB * H), dim3(256), 0, stream,
                           K, V, cuk, Kb, Vb, segArr, T);
        hipLaunchKernelGGL(varlen_attn14, dim3(nQB * H), dim3(256), 0, stream,
                           Q, Kb, Vb, segArr, cuq, cuk, O, T);
    } else {
        int nQT = (T + 63) / 64;
        hipLaunchKernelGGL(varlen_attn_fb, dim3(nQT * H), dim3(256), 0, stream,
                           Q, K, V, cuq, cuk, O, T);
    }
}

// Round 10
// 116.548 us; speedup vs baseline: 1.4869x; 1.0621x over previous
//
#include <hip/hip_runtime.h>

// VarlenAttention MI355X — FINAL (r15 = r11 revert, measured best 118.5us).
// Session ledger: r7 conflicts->0 neutral; r8 split-K -5; r9 swapped-MFMA
// VALU-cut neutral; r10/r13 global-direct -2x (latency-serialized, confirmed
// twice); r12 deeper-pipeline+setprio neutral; r14 in-wave 2-chunk ILP -5.
// Only r11's two changes paid: (1) XCD-ALIGNED WORKSPACE — prepass block map
// chunk*H+h makes writer XCD == reader XCD == h%8, so staging loads hit the
// local L2; (2) ONE barrier per chunk via double-buffered LDS (loads issued
// before compute, LDS-write of next chunk after compute, other buffer).
// Attn kernel ~39us is latency-bound (MfmaUtil ~7%, VALUBusy ~25%, 3
// blocks/CU grid-capped); ~75.7us of the total is harness fill/restore
// (256MiB ws re-poison), present regardless of workspace use (verified r6).
// Keeps: swapped-operand MFMA (S^T, no sP roundtrip), pi-permuted Vb,
// exp2-folded softmax (fixed-max), XOR-swizzled conflict-free LDS.
constexpr int NSEG = 8;
constexpr int H    = 16;
constexpr int D    = 64;
constexpr int BK   = 64;
constexpr int LDKP = D + 8;   // prepass/fallback padded layout

typedef __attribute__((ext_vector_type(8))) short short8v;
typedef __attribute__((ext_vector_type(4))) short short4v;
typedef __attribute__((ext_vector_type(4))) float floatx4;

__device__ inline short f2bf(float f) {  // RNE fp32 -> bf16
    union { float f; unsigned u; } x; x.f = f;
    unsigned r = x.u + 0x7FFFu + ((x.u >> 16) & 1u);
    return (short)(r >> 16);
}

__device__ inline unsigned cvtpk(float lo, float hi) {  // 2 f32 -> packed bf16x2
    unsigned r;
    asm("v_cvt_pk_bf16_f32 %0, %1, %2" : "=v"(r) : "v"(lo), "v"(hi));
    return r;
}

// ---- pre-pass: Kb[h][t][d], Vb[h][d][pi(t)], segArr[t] --------------------
// blockIdx = chunk*H + h -> XCD = h%8 == the XCD that will READ head h
// (attn blockIdx = qb*H + h). V column permutation per 8-key group t8:
// first 4 keys at c0, last 4 at c0+8, c0 = (t8&32)|((t8&8)<<1)|((t8&16)>>2).
__global__ __launch_bounds__(256)
void prepass_kv(const float* __restrict__ K, const float* __restrict__ V,
                const int* __restrict__ cuk,
                short* __restrict__ Kb, short* __restrict__ Vb,
                int* __restrict__ segArr, int T)
{
    __shared__ short sVT[D][LDKP];
    const int tid = threadIdx.x;
    const int h  = blockIdx.x & (H - 1);
    const int t0 = (blockIdx.x >> 4) << 6;
    #pragma unroll
    for (int it = 0; it < 2; ++it) {
        int s  = tid + it * 256;
        int tl = s >> 3;
        int d8 = (s & 7) << 3;
        int t  = t0 + tl;
        const float* kp = K + ((size_t)t * H + h) * D + d8;
        float4 a = *(const float4*)kp;
        float4 b = *(const float4*)(kp + 4);
        short8v ks;
        ks[0]=f2bf(a.x); ks[1]=f2bf(a.y); ks[2]=f2bf(a.z); ks[3]=f2bf(a.w);
        ks[4]=f2bf(b.x); ks[5]=f2bf(b.y); ks[6]=f2bf(b.z); ks[7]=f2bf(b.w);
        *(short8v*)&Kb[((size_t)h * T + t) * D + d8] = ks;
        const float* vp = V + ((size_t)t * H + h) * D + d8;
        float4 c = *(const float4*)vp;
        float4 e = *(const float4*)(vp + 4);
        sVT[d8+0][tl]=f2bf(c.x); sVT[d8+1][tl]=f2bf(c.y);
        sVT[d8+2][tl]=f2bf(c.z); sVT[d8+3][tl]=f2bf(c.w);
        sVT[d8+4][tl]=f2bf(e.x); sVT[d8+5][tl]=f2bf(e.y);
        sVT[d8+6][tl]=f2bf(e.z); sVT[d8+7][tl]=f2bf(e.w);
    }
    if (h == 0 && tid < 64) {
        int t = t0 + tid;
        int s = 0;
        #pragma unroll
        for (int i = 1; i < NSEG; ++i) s += (t >= cuk[i]) ? 1 : 0;
        segArr[t] = s;
    }
    __syncthreads();
    #pragma unroll
    for (int it = 0; it < 2; ++it) {
        int s  = tid + it * 256;
        int d  = s >> 3;
        int t8 = (s & 7) << 3;
        int c0 = (t8 & 32) | ((t8 & 8) << 1) | ((t8 & 16) >> 2);  // pi^-1
        short* vb = &Vb[((size_t)h * D + d) * T + t0];
        *(short4v*)&vb[c0]     = *(const short4v*)&sVT[d][t8];
        *(short4v*)&vb[c0 + 8] = *(const short4v*)&sVT[d][t8 + 4];
    }
}

// ---- main: swapped-MFMA flash, double-buffered LDS, 1 barrier/chunk -------
__global__ __launch_bounds__(256)
void varlen_attn11(const float* __restrict__ Q,
                   const short* __restrict__ Kb, const short* __restrict__ Vb,
                   const int* __restrict__ segArr,
                   const int* __restrict__ cuq, const int* __restrict__ cuk,
                   float* __restrict__ O, int T)
{
    // 32KB: sK[2][64][64] + sVT[2][64][64] (XOR-swizzled slots), reused
    // post-loop as the fp32 O-transpose scratch (stride 68).
    __shared__ __align__(16) char smem[32768];
    short* sKb = reinterpret_cast<short*>(smem);            // [2][4096]
    short* sVb = reinterpret_cast<short*>(smem + 16384);    // [2][4096]
    float* fsc = reinterpret_cast<float*>(smem);

    const int tid  = threadIdx.x;
    const int lane = tid & 63;
    const int w    = tid >> 6;
    const int quad = lane >> 4;
    const int l15  = lane & 15;
    const int h    = blockIdx.x & (H - 1);
    const int t0   = (blockIdx.x >> 4) << 6;

    const int q1 = cuq[1], q2 = cuq[2], q3 = cuq[3], q4 = cuq[4],
              q5 = cuq[5], q6 = cuq[6], q7 = cuq[7];
    const int c0 = cuk[0], c1 = cuk[1], c2 = cuk[2], c3 = cuk[3], c4 = cuk[4],
              c5 = cuk[5], c6 = cuk[6], c7 = cuk[7], c8 = cuk[8];

    // block k-span (block-uniform -> uniform barrier trip count)
    int tB = t0 + 63;
    int sA = (t0>=q1)+(t0>=q2)+(t0>=q3)+(t0>=q4)+(t0>=q5)+(t0>=q6)+(t0>=q7);
    int sB = (tB>=q1)+(tB>=q2)+(tB>=q3)+(tB>=q4)+(tB>=q5)+(tB>=q6)+(tB>=q7);
    int k_start = c0;
    k_start = (sA>0)?c1:k_start; k_start = (sA>1)?c2:k_start;
    k_start = (sA>2)?c3:k_start; k_start = (sA>3)?c4:k_start;
    k_start = (sA>4)?c5:k_start; k_start = (sA>5)?c6:k_start;
    k_start = (sA>6)?c7:k_start;
    int k_end = c1;
    k_end = (sB>0)?c2:k_end; k_end = (sB>1)?c3:k_end;
    k_end = (sB>2)?c4:k_end; k_end = (sB>3)?c5:k_end;
    k_end = (sB>4)?c6:k_end; k_end = (sB>5)?c7:k_end;
    k_end = (sB>6)?c8:k_end;

    // this lane's q (S^T: q = l15 column), its segment id
    const int qrow = t0 + 16 * w + l15;
    const int segq = (qrow>=q1)+(qrow>=q2)+(qrow>=q3)+(qrow>=q4)
                   + (qrow>=q5)+(qrow>=q6)+(qrow>=q7);

    // Q B-fragment, pre-scaled by (1/8)*log2(e); C-init -8*log2(e) -> bare exp2
    const float SC = 0.125f * 1.44269504f;
    const float* qp = Q + ((size_t)qrow * H + h) * D + quad * 8;
    short8v aQ0, aQ1;
    {
        float4 a = *(const float4*)(qp);
        float4 b = *(const float4*)(qp + 4);
        float4 c = *(const float4*)(qp + 32);
        float4 e = *(const float4*)(qp + 36);
        aQ0[0]=f2bf(a.x*SC); aQ0[1]=f2bf(a.y*SC); aQ0[2]=f2bf(a.z*SC); aQ0[3]=f2bf(a.w*SC);
        aQ0[4]=f2bf(b.x*SC); aQ0[5]=f2bf(b.y*SC); aQ0[6]=f2bf(b.z*SC); aQ0[7]=f2bf(b.w*SC);
        aQ1[0]=f2bf(c.x*SC); aQ1[1]=f2bf(c.y*SC); aQ1[2]=f2bf(c.z*SC); aQ1[3]=f2bf(c.w*SC);
        aQ1[4]=f2bf(e.x*SC); aQ1[5]=f2bf(e.y*SC); aQ1[6]=f2bf(e.z*SC); aQ1[7]=f2bf(e.w*SC);
    }

    const short* Kbh = Kb + (size_t)h * T * D;
    const short* Vbh = Vb + (size_t)h * D * T;
    const int key0 = tid >> 3;                         // 0..31
    const int e8   = (tid & 7) << 3;                   // 0..56
    const int slA  = (((tid & 7) ^ (key0 & 7)) << 3);  // swizzled write slot
    const int sw3  = (l15 & 7) << 3;                   // swizzled read offset

    short8v rk0, rk1, rv0, rv1;
    int4 sgC[4], sgN[4];

    auto LOADC = [&](int kc_) {   // register prefetch of chunk kc_
        rk0 = *(const short8v*)(Kbh + (size_t)(kc_ + key0)      * D + e8);
        rk1 = *(const short8v*)(Kbh + (size_t)(kc_ + 32 + key0) * D + e8);
        rv0 = *(const short8v*)(Vbh + (size_t)key0        * T + kc_ + e8);
        rv1 = *(const short8v*)(Vbh + (size_t)(32 + key0) * T + kc_ + e8);
        #pragma unroll
        for (int nt = 0; nt < 4; ++nt)
            sgN[nt] = *(const int4*)(segArr + kc_ + nt * 16 + quad * 4);
    };
    auto WRITEC = [&](int buf) {  // regs -> swizzled LDS buffer `buf`
        short* sk = sKb + buf * (BK * D);
        short* sv = sVb + buf * (BK * D);
        *(short8v*)&sk[ key0       * D + slA] = rk0;
        *(short8v*)&sk[(key0 + 32) * D + slA] = rk1;   // (key0+32)&7 == key0&7
        *(short8v*)&sv[ key0       * BK + slA] = rv0;  // rows here are d
        *(short8v*)&sv[(key0 + 32) * BK + slA] = rv1;
    };

    floatx4 o[4];
    #pragma unroll
    for (int nt = 0; nt < 4; ++nt) o[nt] = (floatx4){0.f, 0.f, 0.f, 0.f};
    float l_r = 0.f;

    const float C0 = -11.54156032f;   // -8 * log2(e)
    const int kc0 = k_start & ~(BK - 1);

    LOADC(kc0);
    #pragma unroll
    for (int nt = 0; nt < 4; ++nt) sgC[nt] = sgN[nt];
    WRITEC(0);

    int cur = 0;
    for (int kc = kc0; kc < k_end; kc += BK) {
        __syncthreads();                      // ONE barrier per chunk:
        const bool more = (kc + BK) < k_end;  // prev iter fully done (reads of
        if (more) LOADC(kc + BK);             // buf cur^1 + writes of buf cur)

        // ---- S^T = K (Q*log2e)^T - 8*log2e ----
        const short* sk = sKb + cur * (BK * D);
        floatx4 sacc[4];
        #pragma unroll
        for (int nt = 0; nt < 4; ++nt) {
            const short* kr = &sk[(nt * 16 + l15) * D];
            short8v a0 = *(const short8v*)(kr + (( quad      << 3) ^ sw3));
            short8v a1 = *(const short8v*)(kr + (((quad + 4) << 3) ^ sw3));
            sacc[nt] = (floatx4){C0, C0, C0, C0};
            sacc[nt] = __builtin_amdgcn_mfma_f32_16x16x32_bf16(a0, aQ0, sacc[nt], 0, 0, 0);
            sacc[nt] = __builtin_amdgcn_mfma_f32_16x16x32_bf16(a1, aQ1, sacc[nt], 0, 0, 0);
        }

        // ---- mask + exp2 + pack to PV B-operand, all in registers ----
        unsigned pk[8];
        #pragma unroll
        for (int nt = 0; nt < 4; ++nt) {
            const int4 s = sgC[nt];
            float p0 = (s.x == segq) ? __builtin_amdgcn_exp2f(sacc[nt][0]) : 0.f;
            float p1 = (s.y == segq) ? __builtin_amdgcn_exp2f(sacc[nt][1]) : 0.f;
            float p2 = (s.z == segq) ? __builtin_amdgcn_exp2f(sacc[nt][2]) : 0.f;
            float p3 = (s.w == segq) ? __builtin_amdgcn_exp2f(sacc[nt][3]) : 0.f;
            l_r += (p0 + p1) + (p2 + p3);
            pk[nt * 2]     = cvtpk(p0, p1);
            pk[nt * 2 + 1] = cvtpk(p2, p3);
        }
        union BP { unsigned u[4]; short8v s; };
        BP blo, bhi;
        blo.u[0] = pk[0]; blo.u[1] = pk[1]; blo.u[2] = pk[2]; blo.u[3] = pk[3];
        bhi.u[0] = pk[4]; bhi.u[1] = pk[5]; bhi.u[2] = pk[6]; bhi.u[3] = pk[7];

        // ---- O^T += V^T P^T (Vb columns pre-permuted to match bP k-slots) ----
        const short* sv = sVb + cur * (BK * D);
        #pragma unroll
        for (int ntd = 0; ntd < 4; ++ntd) {
            const short* vr = &sv[(ntd * 16 + l15) * BK];
            short8v v0 = *(const short8v*)(vr + (( quad      << 3) ^ sw3));
            short8v v1 = *(const short8v*)(vr + (((quad + 4) << 3) ^ sw3));
            o[ntd] = __builtin_amdgcn_mfma_f32_16x16x32_bf16(v0, blo.s, o[ntd], 0, 0, 0);
            o[ntd] = __builtin_amdgcn_mfma_f32_16x16x32_bf16(v1, bhi.s, o[ntd], 0, 0, 0);
        }

        // ---- stage next chunk into the other buffer (no extra barrier) ----
        if (more) {
            WRITEC(cur ^ 1);
            #pragma unroll
            for (int nt = 0; nt < 4; ++nt) sgC[nt] = sgN[nt];
        }
        cur ^= 1;
    }

    // ---- epilogue: l reduce over quads; O^T -> O via LDS scratch ----
    l_r += __shfl_xor(l_r, 16);
    l_r += __shfl_xor(l_r, 32);
    const float linv = 1.0f / l_r;

    __syncthreads();              // all loop LDS reads done; reuse smem as fp32
    #pragma unroll
    for (int ntd = 0; ntd < 4; ++ntd)
        #pragma unroll
        for (int r = 0; r < 4; ++r)
            fsc[(16 * w + l15) * 68 + ntd * 16 + quad * 4 + r] = o[ntd][r] * linv;

    // same-wave LDS roundtrip (wave-private rows) -> coalesced float4 stores
    const int rr = lane >> 2;
    const int dc = (lane & 3) << 4;
    const float* fr = &fsc[(16 * w + rr) * 68 + dc];
    float* op = O + ((size_t)(t0 + 16 * w + rr) * H + h) * D + dc;
    #pragma unroll
    for (int i = 0; i < 4; ++i)
        *(float4*)(op + 4 * i) = *(const float4*)(fr + 4 * i);
}

// ---- fallback (self-contained, any T) -------------------------------------
__global__ __launch_bounds__(256)
void varlen_attn_fb(const float* __restrict__ Q, const float* __restrict__ K,
                    const float* __restrict__ V, const int* __restrict__ cuq,
                    const int* __restrict__ cuk, float* __restrict__ O, int T)
{
    __shared__ short sK[BK][LDKP];
    __shared__ short sVT[D][BK + 8];
    __shared__ short sP[4][16][BK + 8];
    __shared__ int   sSegK[BK];
    __shared__ int   sCuQ[NSEG + 1], sCuK[NSEG + 1];

    const int tid  = threadIdx.x;
    const int lane = tid & 63;
    const int w    = tid >> 6;
    const int quad = lane >> 4;
    const int l15  = lane & 15;
    const int h    = blockIdx.x % H;
    const int t0   = (blockIdx.x / H) * 64;

    if (tid <= NSEG) { sCuQ[tid] = cuq[tid]; sCuK[tid] = cuk[tid]; }
    __syncthreads();

    int qrow = t0 + 16 * w + l15; if (qrow >= T) qrow = T - 1;
    const float* qp = Q + ((size_t)qrow * H + h) * D + quad * 8;
    short8v aQ0, aQ1;
    {
        float4 a = *(const float4*)(qp);
        float4 b = *(const float4*)(qp + 4);
        float4 c = *(const float4*)(qp + 32);
        float4 e = *(const float4*)(qp + 36);
        aQ0[0]=f2bf(a.x*0.125f); aQ0[1]=f2bf(a.y*0.125f);
        aQ0[2]=f2bf(a.z*0.125f); aQ0[3]=f2bf(a.w*0.125f);
        aQ0[4]=f2bf(b.x*0.125f); aQ0[5]=f2bf(b.y*0.125f);
        aQ0[6]=f2bf(b.z*0.125f); aQ0[7]=f2bf(b.w*0.125f);
        aQ1[0]=f2bf(c.x*0.125f); aQ1[1]=f2bf(c.y*0.125f);
        aQ1[2]=f2bf(c.z*0.125f); aQ1[3]=f2bf(c.w*0.125f);
        aQ1[4]=f2bf(e.x*0.125f); aQ1[5]=f2bf(e.y*0.125f);
        aQ1[6]=f2bf(e.z*0.125f); aQ1[7]=f2bf(e.w*0.125f);
    }

    int segq[4];
    #pragma unroll
    for (int r = 0; r < 4; ++r) {
        int t = t0 + 16 * w + quad * 4 + r; if (t >= T) t = T - 1;
        int s = 0;
        while (s < NSEG - 1 && t >= sCuQ[s + 1]) ++s;
        segq[r] = s;
    }
    int k_start, k_end;
    {
        int tA = t0; if (tA >= T) tA = T - 1;
        int tB = t0 + 63; if (tB >= T) tB = T - 1;
        int sA = 0; while (sA < NSEG - 1 && tA >= sCuQ[sA + 1]) ++sA;
        int sB = 0; while (sB < NSEG - 1 && tB >= sCuQ[sB + 1]) ++sB;
        k_start = sCuK[sA];
        k_end   = sCuK[sB + 1];
    }

    floatx4 o[4];
    #pragma unroll
    for (int nt = 0; nt < 4; ++nt) o[nt] = (floatx4){0.f, 0.f, 0.f, 0.f};
    float l_r[4] = {0.f, 0.f, 0.f, 0.f};

    for (int kc = k_start; kc < k_end; kc += BK) {
        __syncthreads();
        for (int i = tid; i < BK * D / 4; i += 256) {
            int k = i >> 4;
            int c = (i & 15) << 2;
            int kt = kc + k;
            float4 kv = {0,0,0,0}, vv = {0,0,0,0};
            if (kt < k_end) {
                kv = *(const float4*)&K[((size_t)kt * H + h) * D + c];
                vv = *(const float4*)&V[((size_t)kt * H + h) * D + c];
            }
            short4v ks;
            ks.x=f2bf(kv.x); ks.y=f2bf(kv.y); ks.z=f2bf(kv.z); ks.w=f2bf(kv.w);
            *(short4v*)&sK[k][c] = ks;
            sVT[c+0][k]=f2bf(vv.x); sVT[c+1][k]=f2bf(vv.y);
            sVT[c+2][k]=f2bf(vv.z); sVT[c+3][k]=f2bf(vv.w);
        }
        if (tid < BK) {
            int kt = kc + tid;
            int s = -1;
            if (kt < k_end) { s = 0; while (s < NSEG - 1 && kt >= sCuK[s + 1]) ++s; }
            sSegK[tid] = s;
        }
        __syncthreads();

        floatx4 sacc[4];
        #pragma unroll
        for (int nt = 0; nt < 4; ++nt) {
            sacc[nt] = (floatx4){-8.f, -8.f, -8.f, -8.f};
            short8v b0 = *(const short8v*)&sK[nt * 16 + l15][quad * 8];
            short8v b1 = *(const short8v*)&sK[nt * 16 + l15][32 + quad * 8];
            sacc[nt] = __builtin_amdgcn_mfma_f32_16x16x32_bf16(aQ0, b0, sacc[nt], 0, 0, 0);
            sacc[nt] = __builtin_amdgcn_mfma_f32_16x16x32_bf16(aQ1, b1, sacc[nt], 0, 0, 0);
        }
        #pragma unroll
        for (int nt = 0; nt < 4; ++nt) {
            int segk = sSegK[nt * 16 + l15];
            #pragma unroll
            for (int r = 0; r < 4; ++r) {
                float sc = (segk == segq[r]) ? sacc[nt][r] : -1e30f;
                float p  = __expf(sc);
                l_r[r] += p;
                sP[w][quad * 4 + r][nt * 16 + l15] = f2bf(p);
            }
        }
        short8v aP0 = *(const short8v*)&sP[w][l15][quad * 8];
        short8v aP1 = *(const short8v*)&sP[w][l15][32 + quad * 8];
        #pragma unroll
        for (int nt = 0; nt < 4; ++nt) {
            short8v b0 = *(const short8v*)&sVT[nt * 16 + l15][quad * 8];
            short8v b1 = *(const short8v*)&sVT[nt * 16 + l15][32 + quad * 8];
            o[nt] = __builtin_amdgcn_mfma_f32_16x16x32_bf16(aP0, b0, o[nt], 0, 0, 0);
            o[nt] = __builtin_amdgcn_mfma_f32_16x16x32_bf16(aP1, b1, o[nt], 0, 0, 0);
        }
    }

    #pragma unroll
    for (int off = 1; off < 16; off <<= 1)
        #pragma unroll
        for (int r = 0; r < 4; ++r)
            l_r[r] += __shfl_xor(l_r[r], off);

    #pragma unroll
    for (int r = 0; r < 4; ++r) {
        int trow = t0 + 16 * w + quad * 4 + r;
        if (trow < T) {
            float linv = 1.0f / l_r[r];
            float* op = O + ((size_t)trow * H + h) * D + l15;
            #pragma unroll
            for (int nt = 0; nt < 4; ++nt)
                op[nt * 16] = o[nt][r] * linv;
        }
    }
}

extern "C" void kernel_launch(void* const* d_in, const int* in_sizes, int n_in,
                              void* d_out, int out_size, void* d_ws, size_t ws_size,
                              hipStream_t stream) {
    const float* Q = (const float*)d_in[0];
    const float* K = (const float*)d_in[1];
    const float* V = (const float*)d_in[2];
    const int* cuq = (const int*)d_in[3];
    const int* cuk = (const int*)d_in[4];
    float* O = (float*)d_out;
    (void)n_in; (void)out_size;

    int T = in_sizes[0] / (H * D);
    int nQB = T >> 6;
    size_t need = (size_t)2 * H * T * D * sizeof(short) + (size_t)T * sizeof(int);

    if (ws_size >= need && (T & 63) == 0) {
        short* Kb = (short*)d_ws;
        short* Vb = Kb + (size_t)H * T * D;
        int* segArr = (int*)(Vb + (size_t)H * T * D);
        hipLaunchKernelGGL(prepass_kv, dim3(nQB * H), dim3(256), 0, stream,
                           K, V, cuk, Kb, Vb, segArr, T);
        hipLaunchKernelGGL(varlen_attn11, dim3(nQB * H), dim3(256), 0, stream,
                           Q, Kb, Vb, segArr, cuq, cuk, O, T);
    } else {
        int nQT = (T + 63) / 64;
        hipLaunchKernelGGL(varlen_attn_fb, dim3(nQT * H), dim3(256), 0, stream,
                           Q, K, V, cuq, cuk, O, T);
    }
}